// Round 1
// baseline (403.782 us; speedup 1.0000x reference)
//
#include <hip/hip_runtime.h>
#include <hip/hip_bf16.h>

#define HH 96
#define WW 96
#define CCH 128
#define NPIX 9216          // H*W
#define DDIM 1152          // CCH*9
#define KSTEPS 36          // DDIM/32
#define MTILES 72          // NPIX/128
#define NCHUNKS 24
#define TILES_PER_CHUNK 3  // 72/24
#define CHUNK_STYLES 384   // TILES_PER_CHUNK*128
#define TOTAL_ELEMS 1179648  // 128*96*96

typedef float f32x4 __attribute__((ext_vector_type(4)));
typedef __bf16 bf16x8 __attribute__((ext_vector_type(8)));

__device__ __forceinline__ void gload_lds16(const void* g, void* l) {
  __builtin_amdgcn_global_load_lds((const __attribute__((address_space(1))) void*)g,
                                   (__attribute__((address_space(3))) void*)l, 16, 0, 0);
}

// Build patch matrix P[n][d], d = c*9 + (ki*3+kj). Optionally style inverse norms.
__global__ void build_patches_kernel(const float* __restrict__ f,
                                     __hip_bfloat16* __restrict__ P,
                                     float* __restrict__ rnorm) {
  const int n = blockIdx.x;        // pixel
  const int c = threadIdx.x;       // channel (128 threads)
  const int y = n / WW, x = n % WW;
  const float* fc = f + (size_t)c * NPIX;
  float vals[9];
  float ss = 0.f;
#pragma unroll
  for (int ki = 0; ki < 3; ++ki) {
    int yy = y + ki - 1;
#pragma unroll
    for (int kj = 0; kj < 3; ++kj) {
      int xx = x + kj - 1;
      float v = (yy >= 0 && yy < HH && xx >= 0 && xx < WW) ? fc[yy * WW + xx] : 0.f;
      vals[ki * 3 + kj] = v;
      ss += v * v;
    }
  }
  __hip_bfloat16* dst = P + (size_t)n * DDIM + c * 9;
#pragma unroll
  for (int t = 0; t < 9; ++t) dst[t] = __float2bfloat16(vals[t]);
  if (rnorm != nullptr) {
    __shared__ float red[128];
    red[c] = ss;
    __syncthreads();
#pragma unroll
    for (int s = 64; s > 0; s >>= 1) {
      if (c < s) red[c] += red[c + s];
      __syncthreads();
    }
    if (c == 0) rnorm[n] = 1.0f / fmaxf(sqrtf(red[0]), 1e-12f);
  }
}

// Fused GEMM + running argmax. Block tile: 128 rows x 384 styles (3 N-tiles of 128).
// 4 waves; wave tile = 32 rows x 128 cols (2 M-frags x 8 N-frags of 16x16x32 MFMA).
__global__ __launch_bounds__(256, 2)
void gemm_argmax_kernel(const __hip_bfloat16* __restrict__ Pc,
                        const __hip_bfloat16* __restrict__ Ps,
                        const float* __restrict__ rnorm,
                        float* __restrict__ bvp, int* __restrict__ bip) {
  __shared__ int4 smem4[2048];  // 32 KB: 2 bufs x (A 8KB + B 8KB)
  char* smem = (char*)smem4;
  const int tid = threadIdx.x;
  const int wid = tid >> 6;
  const int lane = tid & 63;
  const int l15 = lane & 15;
  const int lg = lane >> 4;
  const int mtile = blockIdx.x;   // 0..71
  const int chunk = blockIdx.y;   // 0..23
  const int bm0 = mtile * 128;
  const int sbase = chunk * CHUNK_STYLES;

  // staging map: thread -> (row = tid/4, slot p = tid%4), swizzled source k-group
  const int srow = tid >> 2;
  const int sp = tid & 3;
  const int sg = sp ^ ((srow >> 1) & 3);
  const __hip_bfloat16* pa0 = Pc + (size_t)(bm0 + srow) * DDIM + sg * 8;
  const __hip_bfloat16* pb0 = Ps + (size_t)(sbase + srow) * DDIM + sg * 8;
  const int wbase = (tid & ~63) * 16;  // wave-uniform LDS byte base

  // fragment read byte offsets (swizzled), within a 16KB buffer
  int aro[2], bro[8];
#pragma unroll
  for (int mf = 0; mf < 2; ++mf) {
    int r = wid * 32 + mf * 16 + l15;
    aro[mf] = r * 64 + ((lg ^ ((r >> 1) & 3)) << 4);
  }
#pragma unroll
  for (int nf = 0; nf < 8; ++nf) {
    int r = nf * 16 + l15;
    bro[nf] = 8192 + r * 64 + ((lg ^ ((r >> 1) & 3)) << 4);
  }

  auto stage = [&](int buf, int tile, int ks) {
    const size_t koff = (size_t)ks * 32;
    const __hip_bfloat16* pa = pa0 + koff;
    const __hip_bfloat16* pb = pb0 + (size_t)tile * (128 * DDIM) + koff;
    char* la = smem + buf * 16384 + wbase;
    char* lb = la + 8192;
    gload_lds16(pa, la);
    gload_lds16(pa + 64 * DDIM, la + 4096);
    gload_lds16(pb, lb);
    gload_lds16(pb + 64 * DDIM, lb + 4096);
  };

  f32x4 acc[2][8];
  float bestv[2][4];
  int besti[2][4];
#pragma unroll
  for (int mf = 0; mf < 2; ++mf)
#pragma unroll
    for (int r = 0; r < 4; ++r) { bestv[mf][r] = -3.0e38f; besti[mf][r] = 0; }

  int cur = 0;
  stage(0, 0, 0);
  for (int tile = 0; tile < TILES_PER_CHUNK; ++tile) {
#pragma unroll
    for (int mf = 0; mf < 2; ++mf)
#pragma unroll
      for (int nf = 0; nf < 8; ++nf) {
        f32x4 z = {0.f, 0.f, 0.f, 0.f};
        acc[mf][nf] = z;
      }
    for (int ks = 0; ks < KSTEPS; ++ks) {
      __syncthreads();  // buf[cur] staged (vmcnt drained); buf[cur^1] readers done
      int nt = tile, k2 = ks + 1;
      if (k2 == KSTEPS) { k2 = 0; ++nt; }
      if (nt < TILES_PER_CHUNK) stage(cur ^ 1, nt, k2);
      const char* bp = smem + cur * 16384;
      bf16x8 af[2];
#pragma unroll
      for (int mf = 0; mf < 2; ++mf)
        af[mf] = __builtin_bit_cast(bf16x8, *(const int4*)(bp + aro[mf]));
#pragma unroll
      for (int nf = 0; nf < 8; ++nf) {
        bf16x8 bvec = __builtin_bit_cast(bf16x8, *(const int4*)(bp + bro[nf]));
#pragma unroll
        for (int mf = 0; mf < 2; ++mf)
          acc[mf][nf] = __builtin_amdgcn_mfma_f32_16x16x32_bf16(af[mf], bvec, acc[mf][nf], 0, 0, 0);
      }
      cur ^= 1;
    }
    // argmax epilogue for this 128-col tile (cols ascend -> first-max kept)
#pragma unroll
    for (int nf = 0; nf < 8; ++nf) {
      int col = sbase + tile * 128 + nf * 16 + l15;
      float rn = rnorm[col];
#pragma unroll
      for (int mf = 0; mf < 2; ++mf)
#pragma unroll
        for (int r = 0; r < 4; ++r) {
          float v = acc[mf][nf][r] * rn;
          if (v > bestv[mf][r]) { bestv[mf][r] = v; besti[mf][r] = col; }
        }
    }
  }
  // reduce across the 16 lanes (same rows, different cols), min index on ties
#pragma unroll
  for (int mf = 0; mf < 2; ++mf)
#pragma unroll
    for (int r = 0; r < 4; ++r) {
      float v = bestv[mf][r];
      int bi = besti[mf][r];
#pragma unroll
      for (int m = 1; m < 16; m <<= 1) {
        float ov = __shfl_xor(v, m, 64);
        int oi = __shfl_xor(bi, m, 64);
        if (ov > v || (ov == v && oi < bi)) { v = ov; bi = oi; }
      }
      if (l15 == 0) {
        int row = bm0 + wid * 32 + mf * 16 + lg * 4 + r;
        bvp[chunk * NPIX + row] = v;
        bip[chunk * NPIX + row] = bi;
      }
    }
}

__global__ void merge_best_kernel(const float* __restrict__ bvp, const int* __restrict__ bip,
                                  int* __restrict__ best) {
  int n = blockIdx.x * 256 + threadIdx.x;
  if (n >= NPIX) return;
  float v = -3.0e38f;
  int b = 0;
  for (int c = 0; c < NCHUNKS; ++c) {  // ascending cols: strict > keeps first max
    float vv = bvp[c * NPIX + n];
    int ii = bip[c * NPIX + n];
    if (vv > v || (vv == v && ii < b)) { v = vv; b = ii; }
  }
  best[n] = b;
}

__global__ void recon_mse_kernel(const float* __restrict__ content,
                                 const float* __restrict__ style,
                                 const int* __restrict__ best,
                                 float* __restrict__ out) {
  int idx = blockIdx.x * 256 + threadIdx.x;
  float sq = 0.f;
  if (idx < TOTAL_ELEMS) {
    int c = idx / NPIX;
    int pix = idx - c * NPIX;
    int y = pix / WW, x = pix - (pix / WW) * WW;
    float sum = 0.f, cnt = 0.f;
#pragma unroll
    for (int ki = 0; ki < 3; ++ki) {
      int yn = y - ki + 1;
      if (yn < 0 || yn >= HH) continue;
#pragma unroll
      for (int kj = 0; kj < 3; ++kj) {
        int xn = x - kj + 1;
        if (xn < 0 || xn >= WW) continue;
        cnt += 1.f;
        int m = best[yn * WW + xn];
        int ys = m / WW, xs = m - (m / WW) * WW;
        int sy = ys + ki - 1, sx = xs + kj - 1;
        if (sy >= 0 && sy < HH && sx >= 0 && sx < WW)
          sum += style[(size_t)c * NPIX + sy * WW + sx];
      }
    }
    float recon = sum / (cnt + 1e-8f);
    float d = content[idx] - recon;
    sq = d * d;
  }
#pragma unroll
  for (int m = 32; m > 0; m >>= 1) sq += __shfl_down(sq, m, 64);
  __shared__ float wsum[4];
  int lane = threadIdx.x & 63, w = threadIdx.x >> 6;
  if (lane == 0) wsum[w] = sq;
  __syncthreads();
  if (threadIdx.x == 0) {
    float t = wsum[0] + wsum[1] + wsum[2] + wsum[3];
    atomicAdd(out, t * (1.0f / (float)TOTAL_ELEMS));
  }
}

extern "C" void kernel_launch(void* const* d_in, const int* in_sizes, int n_in,
                              void* d_out, int out_size, void* d_ws, size_t ws_size,
                              hipStream_t stream) {
  const float* content = (const float*)d_in[0];
  const float* stylef = (const float*)d_in[1];
  float* out = (float*)d_out;
  char* ws = (char*)d_ws;

  const size_t PS_OFF = 0;
  const size_t PC_OFF = (size_t)NPIX * DDIM * 2;               // 21,233,664
  const size_t RN_OFF = PC_OFF * 2;                            // 42,467,328
  const size_t BEST_OFF = RN_OFF + NPIX * 4;                   // 42,504,192
  const size_t BVP_OFF = BEST_OFF + NPIX * 4;                  // 42,541,056
  const size_t BIP_OFF = BVP_OFF + (size_t)NCHUNKS * NPIX * 4; // 43,425,792

  __hip_bfloat16* Ps = (__hip_bfloat16*)(ws + PS_OFF);
  __hip_bfloat16* Pc = (__hip_bfloat16*)(ws + PC_OFF);
  float* rnorm = (float*)(ws + RN_OFF);
  int* best = (int*)(ws + BEST_OFF);
  float* bvp = (float*)(ws + BVP_OFF);
  int* bip = (int*)(ws + BIP_OFF);

  hipMemsetAsync(d_out, 0, (size_t)out_size * sizeof(float), stream);
  build_patches_kernel<<<NPIX, 128, 0, stream>>>(stylef, Ps, rnorm);
  build_patches_kernel<<<NPIX, 128, 0, stream>>>(content, Pc, nullptr);
  gemm_argmax_kernel<<<dim3(MTILES, NCHUNKS), 256, 0, stream>>>(Pc, Ps, rnorm, bvp, bip);
  merge_best_kernel<<<(NPIX + 255) / 256, 256, 0, stream>>>(bvp, bip, best);
  recon_mse_kernel<<<TOTAL_ELEMS / 256, 256, 0, stream>>>(content, stylef, best, out);
}